// Round 1
// baseline (3319.468 us; speedup 1.0000x reference)
//
#include <hip/hip_runtime.h>

#define N_NODES 100000
#define D 128
#define N_EDGES 640000

// ---------------------------------------------------------------------------
// Kernel 1: out = r0 * x   (also serves as the required d_out init, since the
// harness poisons d_out with 0xAA before every launch)
// ---------------------------------------------------------------------------
__global__ void init_kernel(const float* __restrict__ x,
                            const float* __restrict__ z0,
                            const float* __restrict__ z1,
                            const float* __restrict__ z2,
                            const float* __restrict__ z3,
                            float* __restrict__ out) {
    int i = blockIdx.x * blockDim.x + threadIdx.x;   // float4 index
    const int total4 = N_NODES * D / 4;              // 3,200,000
    if (i >= total4) return;
    float r0 = fmaxf(z0[0], 0.0f);
    float r1 = fmaxf(z1[0], 0.0f);
    float r2 = fmaxf(z2[0], 0.0f);
    float r3 = fmaxf(z3[0], 0.0f);
    float s = r0 / (r0 + r1 + r2 + r3 + 1e-6f);
    float4 v = ((const float4*)x)[i];
    float4 o;
    o.x = s * v.x; o.y = s * v.y; o.z = s * v.z; o.w = s * v.w;
    ((float4*)out)[i] = o;
}

// ---------------------------------------------------------------------------
// Kernel 2: fused scatter for all 3 edge sets.
//   out[src, (c+shift)&127] += r_k * w[e] * x[dst, c]
// 32 lanes per edge, float4 per lane (128 cols). shift implements jnp.roll
// on the scatter side so gathers stay vectorized/aligned.
// Grid: 3 * (N_EDGES/8) blocks of 256 threads (8 edges per block).
// ---------------------------------------------------------------------------
__global__ void scatter_kernel(const float* __restrict__ x,
                               const int* __restrict__ ei1, const float* __restrict__ w1,
                               const int* __restrict__ ei2, const float* __restrict__ w2,
                               const int* __restrict__ ei3, const float* __restrict__ w3,
                               const float* __restrict__ z0,
                               const float* __restrict__ z1,
                               const float* __restrict__ z2,
                               const float* __restrict__ z3,
                               float* __restrict__ out) {
    const int BLOCKS_PER_SET = N_EDGES / 8;          // 80,000 (exact)
    int gb   = blockIdx.x;
    int set  = gb / BLOCKS_PER_SET;                  // 0, 1, 2  (wave-uniform)
    int lb   = gb % BLOCKS_PER_SET;
    int lane = threadIdx.x & 31;
    int e    = lb * 8 + (threadIdx.x >> 5);          // always < N_EDGES

    const int*   ei;
    const float* w;
    int shift;
    if      (set == 0) { ei = ei1; w = w1; shift = 0; }
    else if (set == 1) { ei = ei2; w = w2; shift = 1; }
    else               { ei = ei3; w = w3; shift = 2; }

    // relu-normalized order weights (cheap, broadcast loads)
    float r0 = fmaxf(z0[0], 0.0f);
    float r1 = fmaxf(z1[0], 0.0f);
    float r2 = fmaxf(z2[0], 0.0f);
    float r3 = fmaxf(z3[0], 0.0f);
    float inv = 1.0f / (r0 + r1 + r2 + r3 + 1e-6f);
    float rk  = (set == 0 ? r1 : (set == 1 ? r2 : r3)) * inv;

    int src = ei[e];                 // segment id (row of out)
    int dst = ei[N_EDGES + e];       // gathered row of x
    float scale = rk * w[e];

    float4 v = ((const float4*)(x + (long long)dst * D))[lane];
    float* orow = out + (long long)src * D;

    int base = 4 * lane + shift;
    atomicAdd(&orow[(base    ) & 127], scale * v.x);
    atomicAdd(&orow[(base + 1) & 127], scale * v.y);
    atomicAdd(&orow[(base + 2) & 127], scale * v.z);
    atomicAdd(&orow[(base + 3) & 127], scale * v.w);
}

extern "C" void kernel_launch(void* const* d_in, const int* in_sizes, int n_in,
                              void* d_out, int out_size, void* d_ws, size_t ws_size,
                              hipStream_t stream) {
    const float* x   = (const float*)d_in[0];
    const int*   ei1 = (const int*)  d_in[1];
    const float* w1  = (const float*)d_in[2];
    const int*   ei2 = (const int*)  d_in[3];
    const float* w2  = (const float*)d_in[4];
    const int*   ei3 = (const int*)  d_in[5];
    const float* w3  = (const float*)d_in[6];
    const float* z0  = (const float*)d_in[7];
    const float* z1  = (const float*)d_in[8];
    const float* z2  = (const float*)d_in[9];
    const float* z3  = (const float*)d_in[10];
    float* out = (float*)d_out;

    const int total4 = N_NODES * D / 4;
    init_kernel<<<(total4 + 255) / 256, 256, 0, stream>>>(x, z0, z1, z2, z3, out);

    const int grid = 3 * (N_EDGES / 8);              // 240,000 blocks
    scatter_kernel<<<grid, 256, 0, stream>>>(x, ei1, w1, ei2, w2, ei3, w3,
                                             z0, z1, z2, z3, out);
}

// Round 2
// 791.869 us; speedup vs baseline: 4.1919x; 4.1919x over previous
//
#include <hip/hip_runtime.h>

#define N_NODES 100000
#define D 128
#define N_EDGES 640000
#define TOT_EDGES (3 * N_EDGES)   // 1,920,000

// ---------------------------------------------------------------------------
// Strategy: per-launch CSR build (group edges by src) + atomic-free gather.
// R1 showed 246M device-scope fp32 atomics cost 3.93 GB of beyond-L2 write
// traffic (16 B/atomic) -> 3.2 ms. CSR build needs only 3.84M int atomics;
// gather accumulates in registers, one clean row write per node.
// ---------------------------------------------------------------------------

// ws layout (bytes):
//   counts  : int [N_NODES]     @ 0
//   offsets : int [N_NODES+1]   @ 400000
//   cursors : int [N_NODES]     @ 800008
//   recs    : int2[TOT_EDGES]   @ 1200008   (dst | set<<17, f32 scale)
#define WS_COUNTS   0
#define WS_OFFSETS  400000
#define WS_CURSORS  800008
#define WS_RECS     1200008
#define WS_NEEDED   (WS_RECS + (size_t)TOT_EDGES * 8)

__device__ __forceinline__ void load_r(const float* z0, const float* z1,
                                       const float* z2, const float* z3,
                                       float& r0, float& r1, float& r2, float& r3) {
    r0 = fmaxf(z0[0], 0.0f);
    r1 = fmaxf(z1[0], 0.0f);
    r2 = fmaxf(z2[0], 0.0f);
    r3 = fmaxf(z3[0], 0.0f);
    float inv = 1.0f / (r0 + r1 + r2 + r3 + 1e-6f);
    r0 *= inv; r1 *= inv; r2 *= inv; r3 *= inv;
}

__global__ void zero_counts_kernel(int* __restrict__ counts) {
    int i = blockIdx.x * blockDim.x + threadIdx.x;
    if (i < N_NODES) counts[i] = 0;
}

// One thread per edge (all 3 sets). N_EDGES % 256 == 0 -> `set` is block-uniform.
__global__ void hist_kernel(const int* __restrict__ ei1,
                            const int* __restrict__ ei2,
                            const int* __restrict__ ei3,
                            int* __restrict__ counts) {
    int e = blockIdx.x * blockDim.x + threadIdx.x;
    if (e >= TOT_EDGES) return;
    int set = e / N_EDGES;
    int idx = e - set * N_EDGES;
    const int* ei = (set == 0) ? ei1 : (set == 1) ? ei2 : ei3;
    atomicAdd(&counts[ei[idx]], 1);
}

// Single-block exclusive scan of counts[N_NODES] -> offsets, cursors.
#define SCAN_T 1024
#define SCAN_CHUNK ((N_NODES + SCAN_T - 1) / SCAN_T)   // 98
__global__ void scan_kernel(const int* __restrict__ counts,
                            int* __restrict__ offsets,
                            int* __restrict__ cursors) {
    __shared__ int sdata[SCAN_T];
    int t = threadIdx.x;
    int base = t * SCAN_CHUNK;

    int sum = 0;
    for (int k = 0; k < SCAN_CHUNK; ++k) {
        int idx = base + k;
        if (idx < N_NODES) sum += counts[idx];
    }
    sdata[t] = sum;
    __syncthreads();
    // inclusive scan over 1024 partial sums (iterative doubling)
    for (int off = 1; off < SCAN_T; off <<= 1) {
        int v = (t >= off) ? sdata[t - off] : 0;
        __syncthreads();
        sdata[t] += v;
        __syncthreads();
    }
    int run = sdata[t] - sum;   // exclusive prefix of this thread's chunk
    for (int k = 0; k < SCAN_CHUNK; ++k) {
        int idx = base + k;
        if (idx < N_NODES) {
            offsets[idx] = run;
            cursors[idx] = run;
            run += counts[idx];
        }
    }
    if (t == 0) offsets[N_NODES] = TOT_EDGES;
}

// Scatter edge records into CSR slots. rec.x = dst | (set<<17), rec.y = scale.
__global__ void fill_kernel(const int* __restrict__ ei1, const float* __restrict__ w1,
                            const int* __restrict__ ei2, const float* __restrict__ w2,
                            const int* __restrict__ ei3, const float* __restrict__ w3,
                            const float* __restrict__ z0, const float* __restrict__ z1,
                            const float* __restrict__ z2, const float* __restrict__ z3,
                            int* __restrict__ cursors, int2* __restrict__ recs) {
    int e = blockIdx.x * blockDim.x + threadIdx.x;
    if (e >= TOT_EDGES) return;
    int set = e / N_EDGES;
    int idx = e - set * N_EDGES;

    const int* ei;  const float* w;
    if      (set == 0) { ei = ei1; w = w1; }
    else if (set == 1) { ei = ei2; w = w2; }
    else               { ei = ei3; w = w3; }

    float r0, r1, r2, r3;
    load_r(z0, z1, z2, z3, r0, r1, r2, r3);
    float rk = (set == 0) ? r1 : (set == 1) ? r2 : r3;

    int src = ei[idx];
    int dst = ei[N_EDGES + idx];
    float scale = rk * w[idx];
    int pos = atomicAdd(&cursors[src], 1);
    recs[pos] = make_int2(dst | (set << 17), __float_as_int(scale));
}

// One wave (64 lanes) per node; 2 columns per lane; accumulate in registers.
// roll(x, s, axis=1)[c] == x[(c-s)&127] -> rotated read index.
__global__ void gather_kernel(const float* __restrict__ x,
                              const int* __restrict__ offsets,
                              const int2* __restrict__ recs,
                              const float* __restrict__ z0, const float* __restrict__ z1,
                              const float* __restrict__ z2, const float* __restrict__ z3,
                              float* __restrict__ out) {
    int wid  = (blockIdx.x * blockDim.x + threadIdx.x) >> 6;  // node id
    int lane = threadIdx.x & 63;
    if (wid >= N_NODES) return;

    float r0, r1, r2, r3;
    load_r(z0, z1, z2, z3, r0, r1, r2, r3);

    const float* xrow = x + (size_t)wid * D;
    float acc0 = r0 * xrow[lane];
    float acc1 = r0 * xrow[lane + 64];

    int beg = offsets[wid];
    int end = offsets[wid + 1];
    for (int e = beg; e < end; ++e) {
        int2 rec = recs[e];                       // broadcast (same addr per wave)
        int dst   = rec.x & 0x1FFFF;
        int shift = rec.x >> 17;
        float scale = __int_as_float(rec.y);
        const float* r = x + (size_t)dst * D;
        acc0 += scale * r[(lane      - shift) & 127];
        acc1 += scale * r[(lane + 64 - shift) & 127];
    }
    out[(size_t)wid * D + lane]      = acc0;
    out[(size_t)wid * D + lane + 64] = acc1;
}

// ---------------------------------------------------------------------------
// Fallback (ws too small): R1 atomic scatter path.
// ---------------------------------------------------------------------------
__global__ void init_kernel(const float* __restrict__ x,
                            const float* __restrict__ z0, const float* __restrict__ z1,
                            const float* __restrict__ z2, const float* __restrict__ z3,
                            float* __restrict__ out) {
    int i = blockIdx.x * blockDim.x + threadIdx.x;
    const int total4 = N_NODES * D / 4;
    if (i >= total4) return;
    float r0, r1, r2, r3;
    load_r(z0, z1, z2, z3, r0, r1, r2, r3);
    float4 v = ((const float4*)x)[i];
    float4 o;
    o.x = r0 * v.x; o.y = r0 * v.y; o.z = r0 * v.z; o.w = r0 * v.w;
    ((float4*)out)[i] = o;
}

__global__ void scatter_kernel(const float* __restrict__ x,
                               const int* __restrict__ ei1, const float* __restrict__ w1,
                               const int* __restrict__ ei2, const float* __restrict__ w2,
                               const int* __restrict__ ei3, const float* __restrict__ w3,
                               const float* __restrict__ z0, const float* __restrict__ z1,
                               const float* __restrict__ z2, const float* __restrict__ z3,
                               float* __restrict__ out) {
    const int BLOCKS_PER_SET = N_EDGES / 8;
    int gb   = blockIdx.x;
    int set  = gb / BLOCKS_PER_SET;
    int lb   = gb % BLOCKS_PER_SET;
    int lane = threadIdx.x & 31;
    int e    = lb * 8 + (threadIdx.x >> 5);

    const int* ei;  const float* w;  int shift;
    if      (set == 0) { ei = ei1; w = w1; shift = 0; }
    else if (set == 1) { ei = ei2; w = w2; shift = 1; }
    else               { ei = ei3; w = w3; shift = 2; }

    float r0, r1, r2, r3;
    load_r(z0, z1, z2, z3, r0, r1, r2, r3);
    float rk = (set == 0) ? r1 : (set == 1) ? r2 : r3;

    int src = ei[e];
    int dst = ei[N_EDGES + e];
    float scale = rk * w[e];

    float4 v = ((const float4*)(x + (long long)dst * D))[lane];
    float* orow = out + (long long)src * D;
    int base = 4 * lane + shift;
    atomicAdd(&orow[(base    ) & 127], scale * v.x);
    atomicAdd(&orow[(base + 1) & 127], scale * v.y);
    atomicAdd(&orow[(base + 2) & 127], scale * v.z);
    atomicAdd(&orow[(base + 3) & 127], scale * v.w);
}

extern "C" void kernel_launch(void* const* d_in, const int* in_sizes, int n_in,
                              void* d_out, int out_size, void* d_ws, size_t ws_size,
                              hipStream_t stream) {
    const float* x   = (const float*)d_in[0];
    const int*   ei1 = (const int*)  d_in[1];
    const float* w1  = (const float*)d_in[2];
    const int*   ei2 = (const int*)  d_in[3];
    const float* w2  = (const float*)d_in[4];
    const int*   ei3 = (const int*)  d_in[5];
    const float* w3  = (const float*)d_in[6];
    const float* z0  = (const float*)d_in[7];
    const float* z1  = (const float*)d_in[8];
    const float* z2  = (const float*)d_in[9];
    const float* z3  = (const float*)d_in[10];
    float* out = (float*)d_out;

    if (ws_size >= WS_NEEDED) {
        char* w = (char*)d_ws;
        int*  counts  = (int*) (w + WS_COUNTS);
        int*  offsets = (int*) (w + WS_OFFSETS);
        int*  cursors = (int*) (w + WS_CURSORS);
        int2* recs    = (int2*)(w + WS_RECS);

        zero_counts_kernel<<<(N_NODES + 255) / 256, 256, 0, stream>>>(counts);
        hist_kernel<<<TOT_EDGES / 256, 256, 0, stream>>>(ei1, ei2, ei3, counts);
        scan_kernel<<<1, SCAN_T, 0, stream>>>(counts, offsets, cursors);
        fill_kernel<<<TOT_EDGES / 256, 256, 0, stream>>>(ei1, w1, ei2, w2, ei3, w3,
                                                         z0, z1, z2, z3, cursors, recs);
        gather_kernel<<<(N_NODES * 64) / 256, 256, 0, stream>>>(x, offsets, recs,
                                                                z0, z1, z2, z3, out);
    } else {
        // fallback: atomic scatter (R1)
        const int total4 = N_NODES * D / 4;
        init_kernel<<<(total4 + 255) / 256, 256, 0, stream>>>(x, z0, z1, z2, z3, out);
        scatter_kernel<<<3 * (N_EDGES / 8), 256, 0, stream>>>(x, ei1, w1, ei2, w2, ei3, w3,
                                                              z0, z1, z2, z3, out);
    }
}

// Round 3
// 473.443 us; speedup vs baseline: 7.0113x; 1.6726x over previous
//
#include <hip/hip_runtime.h>

#define N_NODES 100000
#define D 128
#define N_EDGES 640000
#define TOT_EDGES (3 * N_EDGES)   // 1,920,000

#define SCAN_BLOCKS ((N_NODES + 255) / 256)   // 391

// ws layout (bytes), all 8-aligned where needed:
//   counts  : int [N_NODES]      @ 0
//   offsets : int [N_NODES+1]    @ 400000
//   cursors : int [N_NODES]      @ 800008
//   bsum    : int [SCAN_BLOCKS]  @ 1200008
//   bpre    : int [SCAN_BLOCKS]  @ 1201576
//   recs    : int2[TOT_EDGES]    @ 1203144   (dst | set<<17, f32 scale)
#define WS_COUNTS   0
#define WS_OFFSETS  400000
#define WS_CURSORS  800008
#define WS_BSUM     1200008
#define WS_BPRE     1201576
#define WS_RECS     1203144
#define WS_NEEDED   (WS_RECS + (size_t)TOT_EDGES * 8)

__device__ __forceinline__ void load_r(const float* z0, const float* z1,
                                       const float* z2, const float* z3,
                                       float& r0, float& r1, float& r2, float& r3) {
    r0 = fmaxf(z0[0], 0.0f);
    r1 = fmaxf(z1[0], 0.0f);
    r2 = fmaxf(z2[0], 0.0f);
    r3 = fmaxf(z3[0], 0.0f);
    float inv = 1.0f / (r0 + r1 + r2 + r3 + 1e-6f);
    r0 *= inv; r1 *= inv; r2 *= inv; r3 *= inv;
}

// One thread per edge (all 3 sets). N_EDGES % 256 == 0 -> `set` is block-uniform.
__global__ void hist_kernel(const int* __restrict__ ei1,
                            const int* __restrict__ ei2,
                            const int* __restrict__ ei3,
                            int* __restrict__ counts) {
    int e = blockIdx.x * blockDim.x + threadIdx.x;
    if (e >= TOT_EDGES) return;
    int set = e / N_EDGES;
    int idx = e - set * N_EDGES;
    const int* ei = (set == 0) ? ei1 : (set == 1) ? ei2 : ei3;
    atomicAdd(&counts[ei[idx]], 1);
}

// ---- hierarchical scan (3 tiny kernels) -----------------------------------
// scan1: per-block exclusive scan of 256 counts; block total -> bsum[b]
__global__ void scan1_kernel(const int* __restrict__ counts,
                             int* __restrict__ offsets,
                             int* __restrict__ bsum) {
    __shared__ int s[256];
    int t = threadIdx.x;
    int i = blockIdx.x * 256 + t;
    int v = (i < N_NODES) ? counts[i] : 0;
    s[t] = v;
    __syncthreads();
    for (int off = 1; off < 256; off <<= 1) {
        int u = (t >= off) ? s[t - off] : 0;
        __syncthreads();
        s[t] += u;
        __syncthreads();
    }
    if (i < N_NODES) offsets[i] = s[t] - v;       // exclusive within block
    if (t == 255) bsum[blockIdx.x] = s[255];
}

// scan2: single block scans bsum[SCAN_BLOCKS] -> bpre (exclusive)
__global__ void scan2_kernel(const int* __restrict__ bsum,
                             int* __restrict__ bpre) {
    __shared__ int s[512];
    int t = threadIdx.x;                           // 512 threads
    int v = (t < SCAN_BLOCKS) ? bsum[t] : 0;
    s[t] = v;
    __syncthreads();
    for (int off = 1; off < 512; off <<= 1) {
        int u = (t >= off) ? s[t - off] : 0;
        __syncthreads();
        s[t] += u;
        __syncthreads();
    }
    if (t < SCAN_BLOCKS) bpre[t] = s[t] - v;
}

// scan3: add block prefix, materialize offsets + cursors
__global__ void scan3_kernel(int* __restrict__ offsets,
                             const int* __restrict__ bpre,
                             int* __restrict__ cursors) {
    int i = blockIdx.x * 256 + threadIdx.x;
    if (i < N_NODES) {
        int v = offsets[i] + bpre[blockIdx.x];
        offsets[i] = v;
        cursors[i] = v;
    }
    if (i == 0) offsets[N_NODES] = TOT_EDGES;
}

// ---- CSR fill --------------------------------------------------------------
__global__ void fill_kernel(const int* __restrict__ ei1, const float* __restrict__ w1,
                            const int* __restrict__ ei2, const float* __restrict__ w2,
                            const int* __restrict__ ei3, const float* __restrict__ w3,
                            const float* __restrict__ z0, const float* __restrict__ z1,
                            const float* __restrict__ z2, const float* __restrict__ z3,
                            int* __restrict__ cursors, int2* __restrict__ recs) {
    int e = blockIdx.x * blockDim.x + threadIdx.x;
    if (e >= TOT_EDGES) return;
    int set = e / N_EDGES;
    int idx = e - set * N_EDGES;

    const int* ei;  const float* w;
    if      (set == 0) { ei = ei1; w = w1; }
    else if (set == 1) { ei = ei2; w = w2; }
    else               { ei = ei3; w = w3; }

    float r0, r1, r2, r3;
    load_r(z0, z1, z2, z3, r0, r1, r2, r3);
    float rk = (set == 0) ? r1 : (set == 1) ? r2 : r3;

    int src = ei[idx];
    int dst = ei[N_EDGES + idx];
    float scale = rk * w[idx];
    int pos = atomicAdd(&cursors[src], 1);
    recs[pos] = make_int2(dst | (set << 17), __float_as_int(scale));
}

// ---- gather: one wave per node, register accumulate, single row write ------
// roll(x, s, axis=1)[c] == x[(c-s)&127] -> rotated read index.
__global__ void gather_kernel(const float* __restrict__ x,
                              const int* __restrict__ offsets,
                              const int2* __restrict__ recs,
                              const float* __restrict__ z0, const float* __restrict__ z1,
                              const float* __restrict__ z2, const float* __restrict__ z3,
                              float* __restrict__ out) {
    int wid  = (blockIdx.x * blockDim.x + threadIdx.x) >> 6;  // node id
    int lane = threadIdx.x & 63;
    if (wid >= N_NODES) return;

    float r0, r1, r2, r3;
    load_r(z0, z1, z2, z3, r0, r1, r2, r3);

    const float* xrow = x + (size_t)wid * D;
    float acc0 = r0 * xrow[lane];
    float acc1 = r0 * xrow[lane + 64];

    int beg = offsets[wid];
    int end = offsets[wid + 1];
    int e = beg;
    // 2-way unroll: two row fetches in flight per iteration
    for (; e + 1 < end; e += 2) {
        int2 ra = recs[e];
        int2 rb = recs[e + 1];
        int dsta = ra.x & 0x1FFFF, sa = ra.x >> 17;
        int dstb = rb.x & 0x1FFFF, sb = rb.x >> 17;
        float sca = __int_as_float(ra.y);
        float scb = __int_as_float(rb.y);
        const float* pa = x + (size_t)dsta * D;
        const float* pb = x + (size_t)dstb * D;
        float a0 = pa[(lane      - sa) & 127];
        float a1 = pa[(lane + 64 - sa) & 127];
        float b0 = pb[(lane      - sb) & 127];
        float b1 = pb[(lane + 64 - sb) & 127];
        acc0 += sca * a0;
        acc1 += sca * a1;
        acc0 += scb * b0;
        acc1 += scb * b1;
    }
    if (e < end) {
        int2 rec = recs[e];
        int dst   = rec.x & 0x1FFFF;
        int shift = rec.x >> 17;
        float scale = __int_as_float(rec.y);
        const float* r = x + (size_t)dst * D;
        acc0 += scale * r[(lane      - shift) & 127];
        acc1 += scale * r[(lane + 64 - shift) & 127];
    }
    out[(size_t)wid * D + lane]      = acc0;
    out[(size_t)wid * D + lane + 64] = acc1;
}

// ---------------------------------------------------------------------------
// Fallback (ws too small): R1 atomic scatter path.
// ---------------------------------------------------------------------------
__global__ void init_kernel(const float* __restrict__ x,
                            const float* __restrict__ z0, const float* __restrict__ z1,
                            const float* __restrict__ z2, const float* __restrict__ z3,
                            float* __restrict__ out) {
    int i = blockIdx.x * blockDim.x + threadIdx.x;
    const int total4 = N_NODES * D / 4;
    if (i >= total4) return;
    float r0, r1, r2, r3;
    load_r(z0, z1, z2, z3, r0, r1, r2, r3);
    float4 v = ((const float4*)x)[i];
    float4 o;
    o.x = r0 * v.x; o.y = r0 * v.y; o.z = r0 * v.z; o.w = r0 * v.w;
    ((float4*)out)[i] = o;
}

__global__ void scatter_kernel(const float* __restrict__ x,
                               const int* __restrict__ ei1, const float* __restrict__ w1,
                               const int* __restrict__ ei2, const float* __restrict__ w2,
                               const int* __restrict__ ei3, const float* __restrict__ w3,
                               const float* __restrict__ z0, const float* __restrict__ z1,
                               const float* __restrict__ z2, const float* __restrict__ z3,
                               float* __restrict__ out) {
    const int BLOCKS_PER_SET = N_EDGES / 8;
    int gb   = blockIdx.x;
    int set  = gb / BLOCKS_PER_SET;
    int lb   = gb % BLOCKS_PER_SET;
    int lane = threadIdx.x & 31;
    int e    = lb * 8 + (threadIdx.x >> 5);

    const int* ei;  const float* w;  int shift;
    if      (set == 0) { ei = ei1; w = w1; shift = 0; }
    else if (set == 1) { ei = ei2; w = w2; shift = 1; }
    else               { ei = ei3; w = w3; shift = 2; }

    float r0, r1, r2, r3;
    load_r(z0, z1, z2, z3, r0, r1, r2, r3);
    float rk = (set == 0) ? r1 : (set == 1) ? r2 : r3;

    int src = ei[e];
    int dst = ei[N_EDGES + e];
    float scale = rk * w[e];

    float4 v = ((const float4*)(x + (long long)dst * D))[lane];
    float* orow = out + (long long)src * D;
    int base = 4 * lane + shift;
    atomicAdd(&orow[(base    ) & 127], scale * v.x);
    atomicAdd(&orow[(base + 1) & 127], scale * v.y);
    atomicAdd(&orow[(base + 2) & 127], scale * v.z);
    atomicAdd(&orow[(base + 3) & 127], scale * v.w);
}

extern "C" void kernel_launch(void* const* d_in, const int* in_sizes, int n_in,
                              void* d_out, int out_size, void* d_ws, size_t ws_size,
                              hipStream_t stream) {
    const float* x   = (const float*)d_in[0];
    const int*   ei1 = (const int*)  d_in[1];
    const float* w1  = (const float*)d_in[2];
    const int*   ei2 = (const int*)  d_in[3];
    const float* w2  = (const float*)d_in[4];
    const int*   ei3 = (const int*)  d_in[5];
    const float* w3  = (const float*)d_in[6];
    const float* z0  = (const float*)d_in[7];
    const float* z1  = (const float*)d_in[8];
    const float* z2  = (const float*)d_in[9];
    const float* z3  = (const float*)d_in[10];
    float* out = (float*)d_out;

    if (ws_size >= WS_NEEDED) {
        char* w = (char*)d_ws;
        int*  counts  = (int*) (w + WS_COUNTS);
        int*  offsets = (int*) (w + WS_OFFSETS);
        int*  cursors = (int*) (w + WS_CURSORS);
        int*  bsum    = (int*) (w + WS_BSUM);
        int*  bpre    = (int*) (w + WS_BPRE);
        int2* recs    = (int2*)(w + WS_RECS);

        hipMemsetAsync(counts, 0, N_NODES * sizeof(int), stream);
        hist_kernel<<<TOT_EDGES / 256, 256, 0, stream>>>(ei1, ei2, ei3, counts);
        scan1_kernel<<<SCAN_BLOCKS, 256, 0, stream>>>(counts, offsets, bsum);
        scan2_kernel<<<1, 512, 0, stream>>>(bsum, bpre);
        scan3_kernel<<<SCAN_BLOCKS, 256, 0, stream>>>(offsets, bpre, cursors);
        fill_kernel<<<TOT_EDGES / 256, 256, 0, stream>>>(ei1, w1, ei2, w2, ei3, w3,
                                                         z0, z1, z2, z3, cursors, recs);
        gather_kernel<<<(N_NODES * 64 + 255) / 256, 256, 0, stream>>>(x, offsets, recs,
                                                                      z0, z1, z2, z3, out);
    } else {
        const int total4 = N_NODES * D / 4;
        init_kernel<<<(total4 + 255) / 256, 256, 0, stream>>>(x, z0, z1, z2, z3, out);
        scatter_kernel<<<3 * (N_EDGES / 8), 256, 0, stream>>>(x, ei1, w1, ei2, w2, ei3, w3,
                                                              z0, z1, z2, z3, out);
    }
}

// Round 4
// 373.442 us; speedup vs baseline: 8.8888x; 1.2678x over previous
//
#include <hip/hip_runtime.h>

#define N_NODES 100000
#define D 128
#define N_EDGES 640000
#define TOT_EDGES (3 * N_EDGES)   // 1,920,000
#define OVF_CAP 65536

// ---------------------------------------------------------------------------
// FAST PATH ws layout (bytes):
//   ovf_count : int              @ 0
//   (pad to 64)
//   cursors   : int, stride 16 ints (64 B/node — one cache line per node,
//               kills cross-XCD atomic line ping-pong)   @ 64, 6.4 MB
//   ovf       : int4[OVF_CAP]    @ WS_OVF, 1 MB
//   recs      : int2[N_NODES*C]  @ WS_RECS_F  (dst | set<<17, f32 scale)
// ---------------------------------------------------------------------------
#define WS_OVFCNT 0
#define WS_CURS   64
#define WS_OVF    (WS_CURS + (size_t)N_NODES * 64)
#define WS_RECS_F (WS_OVF + (size_t)OVF_CAP * 16)

__device__ __forceinline__ void load_r(const float* z0, const float* z1,
                                       const float* z2, const float* z3,
                                       float& r0, float& r1, float& r2, float& r3) {
    r0 = fmaxf(z0[0], 0.0f);
    r1 = fmaxf(z1[0], 0.0f);
    r2 = fmaxf(z2[0], 0.0f);
    r3 = fmaxf(z3[0], 0.0f);
    float inv = 1.0f / (r0 + r1 + r2 + r3 + 1e-6f);
    r0 *= inv; r1 *= inv; r2 *= inv; r3 *= inv;
}

// ---- fast fill: one pass, no hist/scan. ------------------------------------
__global__ void fillf_kernel(const int* __restrict__ ei1, const float* __restrict__ w1,
                             const int* __restrict__ ei2, const float* __restrict__ w2,
                             const int* __restrict__ ei3, const float* __restrict__ w3,
                             const float* __restrict__ z0, const float* __restrict__ z1,
                             const float* __restrict__ z2, const float* __restrict__ z3,
                             int* __restrict__ cursors, int* __restrict__ ovf_count,
                             int4* __restrict__ ovf, int2* __restrict__ recs, int C) {
    int e = blockIdx.x * blockDim.x + threadIdx.x;
    if (e >= TOT_EDGES) return;
    int set = e / N_EDGES;          // block-uniform (N_EDGES % 256 == 0)
    int idx = e - set * N_EDGES;

    const int* ei;  const float* w;
    if      (set == 0) { ei = ei1; w = w1; }
    else if (set == 1) { ei = ei2; w = w2; }
    else               { ei = ei3; w = w3; }

    float r0, r1, r2, r3;
    load_r(z0, z1, z2, z3, r0, r1, r2, r3);
    float rk = (set == 0) ? r1 : (set == 1) ? r2 : r3;

    int src = ei[idx];
    int dst = ei[N_EDGES + idx];
    float scale = rk * w[idx];

    int pos = atomicAdd(&cursors[src * 16], 1);
    if (pos < C) {
        recs[(size_t)src * C + pos] = make_int2(dst | (set << 17), __float_as_int(scale));
    } else {
        int o = atomicAdd(ovf_count, 1);
        if (o < OVF_CAP) ovf[o] = make_int4(src, dst | (set << 17), __float_as_int(scale), 0);
    }
}

// ---- fast gather: wave per node, shfl-broadcast recs, float2 rows,
//      shift-separated accumulators, single end-of-loop rotation. -----------
__global__ void gatherf_kernel(const float* __restrict__ x,
                               const int* __restrict__ cursors,
                               const int2* __restrict__ recs,
                               const float* __restrict__ z0, const float* __restrict__ z1,
                               const float* __restrict__ z2, const float* __restrict__ z3,
                               float* __restrict__ out, int C) {
    int wid  = (blockIdx.x * blockDim.x + threadIdx.x) >> 6;
    int lane = threadIdx.x & 63;
    if (wid >= N_NODES) return;

    float r0, r1, r2, r3;
    load_r(z0, z1, z2, z3, r0, r1, r2, r3);

    float2 xv = ((const float2*)(x + (size_t)wid * D))[lane];

    int count = cursors[wid * 16];
    if (count > C) count = C;

    int2 myrec = make_int2(0, 0);
    if (lane < count) myrec = recs[(size_t)wid * C + lane];

    float2 a0 = {0.f, 0.f}, a1 = {0.f, 0.f}, a2 = {0.f, 0.f};

    int j = 0;
    for (; j + 1 < count; j += 2) {
        int rxa = __shfl(myrec.x, j),     rya = __shfl(myrec.y, j);
        int rxb = __shfl(myrec.x, j + 1), ryb = __shfl(myrec.y, j + 1);
        int dsta = rxa & 0x1FFFF, sha = rxa >> 17;
        int dstb = rxb & 0x1FFFF, shb = rxb >> 17;
        float sca = __int_as_float(rya);
        float scb = __int_as_float(ryb);
        float2 va = ((const float2*)(x + (size_t)dsta * D))[lane];
        float2 vb = ((const float2*)(x + (size_t)dstb * D))[lane];
        if      (sha == 0) { a0.x += sca * va.x; a0.y += sca * va.y; }
        else if (sha == 1) { a1.x += sca * va.x; a1.y += sca * va.y; }
        else               { a2.x += sca * va.x; a2.y += sca * va.y; }
        if      (shb == 0) { a0.x += scb * vb.x; a0.y += scb * vb.y; }
        else if (shb == 1) { a1.x += scb * vb.x; a1.y += scb * vb.y; }
        else               { a2.x += scb * vb.x; a2.y += scb * vb.y; }
    }
    if (j < count) {
        int rx = __shfl(myrec.x, j), ry = __shfl(myrec.y, j);
        int dst = rx & 0x1FFFF, sh = rx >> 17;
        float sc = __int_as_float(ry);
        float2 v = ((const float2*)(x + (size_t)dst * D))[lane];
        if      (sh == 0) { a0.x += sc * v.x; a0.y += sc * v.y; }
        else if (sh == 1) { a1.x += sc * v.x; a1.y += sc * v.y; }
        else               { a2.x += sc * v.x; a2.y += sc * v.y; }
    }

    // rotate: out[c] = r0*x[c] + a0[c] + a1[(c-1)&127] + a2[(c-2)&127]
    int prev = (lane + 63) & 63;
    float r1y = __shfl(a1.y, prev);
    float r2x = __shfl(a2.x, prev);
    float r2y = __shfl(a2.y, prev);
    float2 o;
    o.x = r0 * xv.x + a0.x + r1y  + r2x;
    o.y = r0 * xv.y + a0.y + a1.x + r2y;
    ((float2*)(out + (size_t)wid * D))[lane] = o;
}

// ---- overflow cleanup: wave per overflow record, atomic add into out. ------
__global__ void ovf_kernel(const float* __restrict__ x,
                           const int* __restrict__ ovf_count,
                           const int4* __restrict__ ovf,
                           float* __restrict__ out) {
    int total_waves = (gridDim.x * blockDim.x) >> 6;
    int gw   = (blockIdx.x * blockDim.x + threadIdx.x) >> 6;
    int lane = threadIdx.x & 63;
    int n = *ovf_count;
    if (n > OVF_CAP) n = OVF_CAP;
    for (int r = gw; r < n; r += total_waves) {
        int4 rec = ovf[r];
        int src = rec.x;
        int dst = rec.y & 0x1FFFF;
        int sh  = rec.y >> 17;
        float sc = __int_as_float(rec.z);
        const float* xr = x + (size_t)dst * D;
        float* orow = out + (size_t)src * D;
        int c0 = 2 * lane, c1 = 2 * lane + 1;
        atomicAdd(&orow[c0], sc * xr[(c0 - sh) & 127]);
        atomicAdd(&orow[c1], sc * xr[(c1 - sh) & 127]);
    }
}

// ===========================================================================
// MID TIER (R3 exact-CSR path) — used if ws too small for the slot table.
// ===========================================================================
#define SCAN_BLOCKS ((N_NODES + 255) / 256)   // 391
#define WS_COUNTS   0
#define WS_OFFSETS  400000
#define WS_CURSORS  800008
#define WS_BSUM     1200008
#define WS_BPRE     1201576
#define WS_RECS     1203144
#define WS_NEEDED_MID (WS_RECS + (size_t)TOT_EDGES * 8)

__global__ void hist_kernel(const int* __restrict__ ei1,
                            const int* __restrict__ ei2,
                            const int* __restrict__ ei3,
                            int* __restrict__ counts) {
    int e = blockIdx.x * blockDim.x + threadIdx.x;
    if (e >= TOT_EDGES) return;
    int set = e / N_EDGES;
    int idx = e - set * N_EDGES;
    const int* ei = (set == 0) ? ei1 : (set == 1) ? ei2 : ei3;
    atomicAdd(&counts[ei[idx]], 1);
}

__global__ void scan1_kernel(const int* __restrict__ counts,
                             int* __restrict__ offsets,
                             int* __restrict__ bsum) {
    __shared__ int s[256];
    int t = threadIdx.x;
    int i = blockIdx.x * 256 + t;
    int v = (i < N_NODES) ? counts[i] : 0;
    s[t] = v;
    __syncthreads();
    for (int off = 1; off < 256; off <<= 1) {
        int u = (t >= off) ? s[t - off] : 0;
        __syncthreads();
        s[t] += u;
        __syncthreads();
    }
    if (i < N_NODES) offsets[i] = s[t] - v;
    if (t == 255) bsum[blockIdx.x] = s[255];
}

__global__ void scan2_kernel(const int* __restrict__ bsum, int* __restrict__ bpre) {
    __shared__ int s[512];
    int t = threadIdx.x;
    int v = (t < SCAN_BLOCKS) ? bsum[t] : 0;
    s[t] = v;
    __syncthreads();
    for (int off = 1; off < 512; off <<= 1) {
        int u = (t >= off) ? s[t - off] : 0;
        __syncthreads();
        s[t] += u;
        __syncthreads();
    }
    if (t < SCAN_BLOCKS) bpre[t] = s[t] - v;
}

__global__ void scan3_kernel(int* __restrict__ offsets,
                             const int* __restrict__ bpre,
                             int* __restrict__ cursors) {
    int i = blockIdx.x * 256 + threadIdx.x;
    if (i < N_NODES) {
        int v = offsets[i] + bpre[blockIdx.x];
        offsets[i] = v;
        cursors[i] = v;
    }
    if (i == 0) offsets[N_NODES] = TOT_EDGES;
}

__global__ void fill_kernel(const int* __restrict__ ei1, const float* __restrict__ w1,
                            const int* __restrict__ ei2, const float* __restrict__ w2,
                            const int* __restrict__ ei3, const float* __restrict__ w3,
                            const float* __restrict__ z0, const float* __restrict__ z1,
                            const float* __restrict__ z2, const float* __restrict__ z3,
                            int* __restrict__ cursors, int2* __restrict__ recs) {
    int e = blockIdx.x * blockDim.x + threadIdx.x;
    if (e >= TOT_EDGES) return;
    int set = e / N_EDGES;
    int idx = e - set * N_EDGES;
    const int* ei;  const float* w;
    if      (set == 0) { ei = ei1; w = w1; }
    else if (set == 1) { ei = ei2; w = w2; }
    else               { ei = ei3; w = w3; }
    float r0, r1, r2, r3;
    load_r(z0, z1, z2, z3, r0, r1, r2, r3);
    float rk = (set == 0) ? r1 : (set == 1) ? r2 : r3;
    int src = ei[idx];
    int dst = ei[N_EDGES + idx];
    float scale = rk * w[idx];
    int pos = atomicAdd(&cursors[src], 1);
    recs[pos] = make_int2(dst | (set << 17), __float_as_int(scale));
}

__global__ void gather_kernel(const float* __restrict__ x,
                              const int* __restrict__ offsets,
                              const int2* __restrict__ recs,
                              const float* __restrict__ z0, const float* __restrict__ z1,
                              const float* __restrict__ z2, const float* __restrict__ z3,
                              float* __restrict__ out) {
    int wid  = (blockIdx.x * blockDim.x + threadIdx.x) >> 6;
    int lane = threadIdx.x & 63;
    if (wid >= N_NODES) return;
    float r0, r1, r2, r3;
    load_r(z0, z1, z2, z3, r0, r1, r2, r3);
    const float* xrow = x + (size_t)wid * D;
    float acc0 = r0 * xrow[lane];
    float acc1 = r0 * xrow[lane + 64];
    int beg = offsets[wid];
    int end = offsets[wid + 1];
    for (int e = beg; e < end; ++e) {
        int2 rec = recs[e];
        int dst   = rec.x & 0x1FFFF;
        int shift = rec.x >> 17;
        float scale = __int_as_float(rec.y);
        const float* r = x + (size_t)dst * D;
        acc0 += scale * r[(lane      - shift) & 127];
        acc1 += scale * r[(lane + 64 - shift) & 127];
    }
    out[(size_t)wid * D + lane]      = acc0;
    out[(size_t)wid * D + lane + 64] = acc1;
}

// ---- last-resort fallback (R1) ---------------------------------------------
__global__ void init_kernel(const float* __restrict__ x,
                            const float* __restrict__ z0, const float* __restrict__ z1,
                            const float* __restrict__ z2, const float* __restrict__ z3,
                            float* __restrict__ out) {
    int i = blockIdx.x * blockDim.x + threadIdx.x;
    const int total4 = N_NODES * D / 4;
    if (i >= total4) return;
    float r0, r1, r2, r3;
    load_r(z0, z1, z2, z3, r0, r1, r2, r3);
    float4 v = ((const float4*)x)[i];
    float4 o;
    o.x = r0 * v.x; o.y = r0 * v.y; o.z = r0 * v.z; o.w = r0 * v.w;
    ((float4*)out)[i] = o;
}

__global__ void scatter_kernel(const float* __restrict__ x,
                               const int* __restrict__ ei1, const float* __restrict__ w1,
                               const int* __restrict__ ei2, const float* __restrict__ w2,
                               const int* __restrict__ ei3, const float* __restrict__ w3,
                               const float* __restrict__ z0, const float* __restrict__ z1,
                               const float* __restrict__ z2, const float* __restrict__ z3,
                               float* __restrict__ out) {
    const int BLOCKS_PER_SET = N_EDGES / 8;
    int gb   = blockIdx.x;
    int set  = gb / BLOCKS_PER_SET;
    int lb   = gb % BLOCKS_PER_SET;
    int lane = threadIdx.x & 31;
    int e    = lb * 8 + (threadIdx.x >> 5);
    const int* ei;  const float* w;  int shift;
    if      (set == 0) { ei = ei1; w = w1; shift = 0; }
    else if (set == 1) { ei = ei2; w = w2; shift = 1; }
    else               { ei = ei3; w = w3; shift = 2; }
    float r0, r1, r2, r3;
    load_r(z0, z1, z2, z3, r0, r1, r2, r3);
    float rk = (set == 0) ? r1 : (set == 1) ? r2 : r3;
    int src = ei[e];
    int dst = ei[N_EDGES + e];
    float scale = rk * w[e];
    float4 v = ((const float4*)(x + (long long)dst * D))[lane];
    float* orow = out + (long long)src * D;
    int base = 4 * lane + shift;
    atomicAdd(&orow[(base    ) & 127], scale * v.x);
    atomicAdd(&orow[(base + 1) & 127], scale * v.y);
    atomicAdd(&orow[(base + 2) & 127], scale * v.z);
    atomicAdd(&orow[(base + 3) & 127], scale * v.w);
}

extern "C" void kernel_launch(void* const* d_in, const int* in_sizes, int n_in,
                              void* d_out, int out_size, void* d_ws, size_t ws_size,
                              hipStream_t stream) {
    const float* x   = (const float*)d_in[0];
    const int*   ei1 = (const int*)  d_in[1];
    const float* w1  = (const float*)d_in[2];
    const int*   ei2 = (const int*)  d_in[3];
    const float* w2  = (const float*)d_in[4];
    const int*   ei3 = (const int*)  d_in[5];
    const float* w3  = (const float*)d_in[6];
    const float* z0  = (const float*)d_in[7];
    const float* z1  = (const float*)d_in[8];
    const float* z2  = (const float*)d_in[9];
    const float* z3  = (const float*)d_in[10];
    float* out = (float*)d_out;
    char* wsc = (char*)d_ws;

    // choose slot capacity from available ws; need C>=28 for negligible overflow
    int C = 0;
    if (ws_size > WS_RECS_F) {
        size_t c = (ws_size - WS_RECS_F) / ((size_t)N_NODES * 8);
        C = (c > 64) ? 64 : (int)c;
    }

    if (C >= 28) {
        int*  cursors   = (int*) (wsc + WS_CURS);
        int*  ovf_count = (int*) (wsc + WS_OVFCNT);
        int4* ovf       = (int4*)(wsc + WS_OVF);
        int2* recs      = (int2*)(wsc + WS_RECS_F);

        hipMemsetAsync(wsc, 0, WS_OVF, stream);   // ovf_count + strided cursors
        fillf_kernel<<<TOT_EDGES / 256, 256, 0, stream>>>(ei1, w1, ei2, w2, ei3, w3,
                                                          z0, z1, z2, z3,
                                                          cursors, ovf_count, ovf, recs, C);
        gatherf_kernel<<<(N_NODES * 64 + 255) / 256, 256, 0, stream>>>(x, cursors, recs,
                                                                       z0, z1, z2, z3, out, C);
        ovf_kernel<<<256, 256, 0, stream>>>(x, ovf_count, ovf, out);
    } else if (ws_size >= WS_NEEDED_MID) {
        int*  counts  = (int*) (wsc + WS_COUNTS);
        int*  offsets = (int*) (wsc + WS_OFFSETS);
        int*  cursors = (int*) (wsc + WS_CURSORS);
        int*  bsum    = (int*) (wsc + WS_BSUM);
        int*  bpre    = (int*) (wsc + WS_BPRE);
        int2* recs    = (int2*)(wsc + WS_RECS);

        hipMemsetAsync(counts, 0, N_NODES * sizeof(int), stream);
        hist_kernel<<<TOT_EDGES / 256, 256, 0, stream>>>(ei1, ei2, ei3, counts);
        scan1_kernel<<<SCAN_BLOCKS, 256, 0, stream>>>(counts, offsets, bsum);
        scan2_kernel<<<1, 512, 0, stream>>>(bsum, bpre);
        scan3_kernel<<<SCAN_BLOCKS, 256, 0, stream>>>(offsets, bpre, cursors);
        fill_kernel<<<TOT_EDGES / 256, 256, 0, stream>>>(ei1, w1, ei2, w2, ei3, w3,
                                                         z0, z1, z2, z3, cursors, recs);
        gather_kernel<<<(N_NODES * 64 + 255) / 256, 256, 0, stream>>>(x, offsets, recs,
                                                                      z0, z1, z2, z3, out);
    } else {
        const int total4 = N_NODES * D / 4;
        init_kernel<<<(total4 + 255) / 256, 256, 0, stream>>>(x, z0, z1, z2, z3, out);
        scatter_kernel<<<3 * (N_EDGES / 8), 256, 0, stream>>>(x, ei1, w1, ei2, w2, ei3, w3,
                                                              z0, z1, z2, z3, out);
    }
}

// Round 5
// 320.589 us; speedup vs baseline: 10.3543x; 1.1649x over previous
//
#include <hip/hip_runtime.h>

#define N_NODES 100000
#define D 128
#define N_EDGES 640000
#define TOT_EDGES (3 * N_EDGES)   // 1,920,000

#define NB   256                  // buckets (node ranges)
#define NPB  391                  // nodes per bucket (256*391 >= 100000)
#define BCAP 9216                 // record capacity per bucket (mean 7500, +20 sigma)
#define OVF_CAP 65536
#define EPB  3072                 // edges per binA block
#define BINA_BLOCKS (TOT_EDGES / EPB)   // 625
#define EPT  (EPB / 256)                // 12 edges per thread

// ---------------- fast-path ws layout (bytes) ----------------
#define WS_OVFCNT 0
#define WS_BCUR   64                         // int, stride 16 ints (64B/bucket), 16384 B
#define WS_BBASE  16448                      // int[256]
#define WS_BNUM   17472                      // int[256]
#define WS_OVF    18496                      // int4[OVF_CAP], 1 MB
#define WS_TMP    1067072                    // int2[NB*BCAP], 18.9 MB
#define WS_FREC   19941440                   // int2[TOT_EDGES], 15.36 MB
#define WS_OFFS   35301440                   // int[N_NODES+1]
#define WS_TOTAL_F 35701444

__device__ __forceinline__ void load_r(const float* z0, const float* z1,
                                       const float* z2, const float* z3,
                                       float& r0, float& r1, float& r2, float& r3) {
    r0 = fmaxf(z0[0], 0.0f);
    r1 = fmaxf(z1[0], 0.0f);
    r2 = fmaxf(z2[0], 0.0f);
    r3 = fmaxf(z3[0], 0.0f);
    float inv = 1.0f / (r0 + r1 + r2 + r3 + 1e-6f);
    r0 *= inv; r1 *= inv; r2 *= inv; r3 *= inv;
}

// ---------------------------------------------------------------------------
// binA: LDS-aggregated binning of all edges into 256 node-range buckets.
// tmp rec: x = dst(17) | set<<17 (2) | local<<19 (9), y = f32 scale.
// ---------------------------------------------------------------------------
__global__ void binA_kernel(const int* __restrict__ ei1, const float* __restrict__ w1,
                            const int* __restrict__ ei2, const float* __restrict__ w2,
                            const int* __restrict__ ei3, const float* __restrict__ w3,
                            const float* __restrict__ z0, const float* __restrict__ z1,
                            const float* __restrict__ z2, const float* __restrict__ z3,
                            int* __restrict__ bcur, int* __restrict__ ovf_count,
                            int4* __restrict__ ovf, int2* __restrict__ tmp) {
    __shared__ int hist[NB];
    __shared__ int base[NB];
    int t = threadIdx.x;
    hist[t] = 0;
    __syncthreads();

    int e0 = blockIdx.x * EPB;
    int rank[EPT];
    int bkt[EPT];

    // phase 1: per-block histogram + in-block rank (load only src)
    for (int k = 0; k < EPT; ++k) {
        int e = e0 + t + k * 256;
        int set = e / N_EDGES;
        int idx = e - set * N_EDGES;
        const int* ei = (set == 0) ? ei1 : (set == 1) ? ei2 : ei3;
        int src = ei[idx];
        int b = src / NPB;
        bkt[k]  = b;
        rank[k] = atomicAdd(&hist[b], 1);
    }
    __syncthreads();

    // phase 2: one global reservation per (block,bucket)
    {
        int h = hist[t];
        base[t] = h ? atomicAdd(&bcur[t * 16], h) : 0;
    }
    __syncthreads();

    float r0, r1, r2, r3;
    load_r(z0, z1, z2, z3, r0, r1, r2, r3);

    // phase 3: write records into reserved chunks (L2-hot reloads of edges)
    for (int k = 0; k < EPT; ++k) {
        int e = e0 + t + k * 256;
        int set = e / N_EDGES;
        int idx = e - set * N_EDGES;
        const int* ei;  const float* w;
        if      (set == 0) { ei = ei1; w = w1; }
        else if (set == 1) { ei = ei2; w = w2; }
        else               { ei = ei3; w = w3; }
        int src = ei[idx];
        int dst = ei[N_EDGES + idx];
        float rk = (set == 0) ? r1 : (set == 1) ? r2 : r3;
        float scale = rk * w[idx];
        int b = bkt[k];
        int local = src - b * NPB;
        int pos = base[b] + rank[k];
        int rx = dst | (set << 17) | (local << 19);
        if (pos < BCAP) {
            tmp[(size_t)b * BCAP + pos] = make_int2(rx, __float_as_int(scale));
        } else {
            int o = atomicAdd(ovf_count, 1);
            if (o < OVF_CAP) ovf[o] = make_int4(src, dst | (set << 17),
                                                __float_as_int(scale), 0);
        }
    }
}

// scanB: exclusive scan of (clamped) bucket counts -> global bucket bases.
__global__ void scanB_kernel(const int* __restrict__ bcur,
                             int* __restrict__ bbase, int* __restrict__ bnum,
                             int* __restrict__ offsets) {
    __shared__ int s[NB];
    int t = threadIdx.x;                   // 256 threads
    int n = bcur[t * 16];
    if (n > BCAP) n = BCAP;
    bnum[t] = n;
    s[t] = n;
    __syncthreads();
    for (int off = 1; off < NB; off <<= 1) {
        int v = (t >= off) ? s[t - off] : 0;
        __syncthreads();
        s[t] += v;
        __syncthreads();
    }
    bbase[t] = s[t] - n;
    if (t == NB - 1) offsets[N_NODES] = s[t];
}

// binB: per-bucket local CSR (LDS degree count + scan), emit dense sorted recs
// + per-node offsets. Scatter stays inside the bucket's ~60KB L2-hot window.
__global__ void binB_kernel(const int2* __restrict__ tmp,
                            const int* __restrict__ bbase, const int* __restrict__ bnum,
                            int2* __restrict__ frecs, int* __restrict__ offsets) {
    __shared__ int d[512];
    __shared__ int s[512];
    __shared__ int cur[NPB];
    int b = blockIdx.x;
    int t = threadIdx.x;
    int n = bnum[b];
    int gbase = bbase[b];

    d[t] = 0; d[t + 256] = 0;
    __syncthreads();
    for (int i = t; i < n; i += 256) {
        int rx = tmp[(size_t)b * BCAP + i].x;
        atomicAdd(&d[(rx >> 19) & 0x1FF], 1);
    }
    __syncthreads();
    s[t] = d[t]; s[t + 256] = d[t + 256];
    __syncthreads();
    for (int off = 1; off < 512; off <<= 1) {
        int v0 = (t       >= off) ? s[t       - off] : 0;
        int v1 = (t + 256 >= off) ? s[t + 256 - off] : 0;
        __syncthreads();
        s[t] += v0; s[t + 256] += v1;
        __syncthreads();
    }
    int node0 = b * NPB;
    for (int l = t; l < NPB; l += 256) {
        int excl = s[l] - d[l];
        cur[l] = excl;
        int node = node0 + l;
        if (node < N_NODES) offsets[node] = gbase + excl;
    }
    __syncthreads();
    for (int i = t; i < n; i += 256) {
        int2 rec = tmp[(size_t)b * BCAP + i];
        int pos = atomicAdd(&cur[(rec.x >> 19) & 0x1FF], 1);
        frecs[gbase + pos] = make_int2(rec.x & 0x7FFFF, rec.y);
    }
}

// ---------------------------------------------------------------------------
// gather: wave per node over dense sorted recs; shfl-broadcast; float2 rows;
// shift-separated accumulators + single end rotation; 4-way unroll for MLP.
// ---------------------------------------------------------------------------
__global__ void gatherd_kernel(const float* __restrict__ x,
                               const int* __restrict__ offsets,
                               const int2* __restrict__ recs,
                               const float* __restrict__ z0, const float* __restrict__ z1,
                               const float* __restrict__ z2, const float* __restrict__ z3,
                               float* __restrict__ out) {
    int wid  = (blockIdx.x * blockDim.x + threadIdx.x) >> 6;
    int lane = threadIdx.x & 63;
    if (wid >= N_NODES) return;

    float r0, r1, r2, r3;
    load_r(z0, z1, z2, z3, r0, r1, r2, r3);

    float2 xv = ((const float2*)(x + (size_t)wid * D))[lane];

    int beg = offsets[wid];
    int end = offsets[wid + 1];
    int count = end - beg;
    int cnt64 = (count < 64) ? count : 64;

    int2 myrec = make_int2(0, 0);
    if (lane < cnt64) myrec = recs[beg + lane];

    float2 a0 = {0.f, 0.f}, a1 = {0.f, 0.f}, a2 = {0.f, 0.f};

    int j = 0;
    for (; j + 3 < cnt64; j += 4) {
        int rxa = __shfl(myrec.x, j),     rya = __shfl(myrec.y, j);
        int rxb = __shfl(myrec.x, j + 1), ryb = __shfl(myrec.y, j + 1);
        int rxc = __shfl(myrec.x, j + 2), ryc = __shfl(myrec.y, j + 2);
        int rxd = __shfl(myrec.x, j + 3), ryd = __shfl(myrec.y, j + 3);
        float2 va = ((const float2*)(x + (size_t)(rxa & 0x1FFFF) * D))[lane];
        float2 vb = ((const float2*)(x + (size_t)(rxb & 0x1FFFF) * D))[lane];
        float2 vc = ((const float2*)(x + (size_t)(rxc & 0x1FFFF) * D))[lane];
        float2 vd = ((const float2*)(x + (size_t)(rxd & 0x1FFFF) * D))[lane];
        int sha = rxa >> 17, shb = rxb >> 17, shc = rxc >> 17, shd = rxd >> 17;
        float sca = __int_as_float(rya), scb = __int_as_float(ryb);
        float scc = __int_as_float(ryc), scd = __int_as_float(ryd);
        if      (sha == 0) { a0.x += sca * va.x; a0.y += sca * va.y; }
        else if (sha == 1) { a1.x += sca * va.x; a1.y += sca * va.y; }
        else               { a2.x += sca * va.x; a2.y += sca * va.y; }
        if      (shb == 0) { a0.x += scb * vb.x; a0.y += scb * vb.y; }
        else if (shb == 1) { a1.x += scb * vb.x; a1.y += scb * vb.y; }
        else               { a2.x += scb * vb.x; a2.y += scb * vb.y; }
        if      (shc == 0) { a0.x += scc * vc.x; a0.y += scc * vc.y; }
        else if (shc == 1) { a1.x += scc * vc.x; a1.y += scc * vc.y; }
        else               { a2.x += scc * vc.x; a2.y += scc * vc.y; }
        if      (shd == 0) { a0.x += scd * vd.x; a0.y += scd * vd.y; }
        else if (shd == 1) { a1.x += scd * vd.x; a1.y += scd * vd.y; }
        else               { a2.x += scd * vd.x; a2.y += scd * vd.y; }
    }
    for (; j < cnt64; ++j) {
        int rx = __shfl(myrec.x, j), ry = __shfl(myrec.y, j);
        float2 v = ((const float2*)(x + (size_t)(rx & 0x1FFFF) * D))[lane];
        int sh = rx >> 17;
        float sc = __int_as_float(ry);
        if      (sh == 0) { a0.x += sc * v.x; a0.y += sc * v.y; }
        else if (sh == 1) { a1.x += sc * v.x; a1.y += sc * v.y; }
        else               { a2.x += sc * v.x; a2.y += sc * v.y; }
    }
    for (int q = 64; q < count; ++q) {     // rare high-degree tail
        int2 rec = recs[beg + q];          // wave-uniform broadcast load
        float2 v = ((const float2*)(x + (size_t)(rec.x & 0x1FFFF) * D))[lane];
        int sh = rec.x >> 17;
        float sc = __int_as_float(rec.y);
        if      (sh == 0) { a0.x += sc * v.x; a0.y += sc * v.y; }
        else if (sh == 1) { a1.x += sc * v.x; a1.y += sc * v.y; }
        else               { a2.x += sc * v.x; a2.y += sc * v.y; }
    }

    // out[c] = r0*x[c] + a0[c] + a1[(c-1)&127] + a2[(c-2)&127]
    int prev = (lane + 63) & 63;
    float r1y = __shfl(a1.y, prev);
    float r2x = __shfl(a2.x, prev);
    float r2y = __shfl(a2.y, prev);
    float2 o;
    o.x = r0 * xv.x + a0.x + r1y  + r2x;
    o.y = r0 * xv.y + a0.y + a1.x + r2y;
    ((float2*)(out + (size_t)wid * D))[lane] = o;
}

// overflow cleanup: wave per record, atomic add (expected ~0 records)
__global__ void ovf_kernel(const float* __restrict__ x,
                           const int* __restrict__ ovf_count,
                           const int4* __restrict__ ovf,
                           float* __restrict__ out) {
    int total_waves = (gridDim.x * blockDim.x) >> 6;
    int gw   = (blockIdx.x * blockDim.x + threadIdx.x) >> 6;
    int lane = threadIdx.x & 63;
    int n = *ovf_count;
    if (n > OVF_CAP) n = OVF_CAP;
    for (int r = gw; r < n; r += total_waves) {
        int4 rec = ovf[r];
        int src = rec.x;
        int dst = rec.y & 0x1FFFF;
        int sh  = (rec.y >> 17) & 3;
        float sc = __int_as_float(rec.z);
        const float* xr = x + (size_t)dst * D;
        float* orow = out + (size_t)src * D;
        int c0 = 2 * lane, c1 = 2 * lane + 1;
        atomicAdd(&orow[c0], sc * xr[(c0 - sh) & 127]);
        atomicAdd(&orow[c1], sc * xr[(c1 - sh) & 127]);
    }
}

// ===========================================================================
// MID TIER fallback (R3 exact-CSR path), used if ws too small for fast path.
// ===========================================================================
#define SCAN_BLOCKS ((N_NODES + 255) / 256)   // 391
#define WS_COUNTS   0
#define WS_OFFSETS  400000
#define WS_CURSORS  800008
#define WS_BSUM     1200008
#define WS_BPRE     1201576
#define WS_RECS     1203144
#define WS_NEEDED_MID (WS_RECS + (size_t)TOT_EDGES * 8)

__global__ void hist_kernel(const int* __restrict__ ei1, const int* __restrict__ ei2,
                            const int* __restrict__ ei3, int* __restrict__ counts) {
    int e = blockIdx.x * blockDim.x + threadIdx.x;
    if (e >= TOT_EDGES) return;
    int set = e / N_EDGES;
    int idx = e - set * N_EDGES;
    const int* ei = (set == 0) ? ei1 : (set == 1) ? ei2 : ei3;
    atomicAdd(&counts[ei[idx]], 1);
}

__global__ void scan1_kernel(const int* __restrict__ counts,
                             int* __restrict__ offsets, int* __restrict__ bsum) {
    __shared__ int s[256];
    int t = threadIdx.x;
    int i = blockIdx.x * 256 + t;
    int v = (i < N_NODES) ? counts[i] : 0;
    s[t] = v;
    __syncthreads();
    for (int off = 1; off < 256; off <<= 1) {
        int u = (t >= off) ? s[t - off] : 0;
        __syncthreads();
        s[t] += u;
        __syncthreads();
    }
    if (i < N_NODES) offsets[i] = s[t] - v;
    if (t == 255) bsum[blockIdx.x] = s[255];
}

__global__ void scan2_kernel(const int* __restrict__ bsum, int* __restrict__ bpre) {
    __shared__ int s[512];
    int t = threadIdx.x;
    int v = (t < SCAN_BLOCKS) ? bsum[t] : 0;
    s[t] = v;
    __syncthreads();
    for (int off = 1; off < 512; off <<= 1) {
        int u = (t >= off) ? s[t - off] : 0;
        __syncthreads();
        s[t] += u;
        __syncthreads();
    }
    if (t < SCAN_BLOCKS) bpre[t] = s[t] - v;
}

__global__ void scan3_kernel(int* __restrict__ offsets, const int* __restrict__ bpre,
                             int* __restrict__ cursors) {
    int i = blockIdx.x * 256 + threadIdx.x;
    if (i < N_NODES) {
        int v = offsets[i] + bpre[blockIdx.x];
        offsets[i] = v;
        cursors[i] = v;
    }
    if (i == 0) offsets[N_NODES] = TOT_EDGES;
}

__global__ void fill_kernel(const int* __restrict__ ei1, const float* __restrict__ w1,
                            const int* __restrict__ ei2, const float* __restrict__ w2,
                            const int* __restrict__ ei3, const float* __restrict__ w3,
                            const float* __restrict__ z0, const float* __restrict__ z1,
                            const float* __restrict__ z2, const float* __restrict__ z3,
                            int* __restrict__ cursors, int2* __restrict__ recs) {
    int e = blockIdx.x * blockDim.x + threadIdx.x;
    if (e >= TOT_EDGES) return;
    int set = e / N_EDGES;
    int idx = e - set * N_EDGES;
    const int* ei;  const float* w;
    if      (set == 0) { ei = ei1; w = w1; }
    else if (set == 1) { ei = ei2; w = w2; }
    else               { ei = ei3; w = w3; }
    float r0, r1, r2, r3;
    load_r(z0, z1, z2, z3, r0, r1, r2, r3);
    float rk = (set == 0) ? r1 : (set == 1) ? r2 : r3;
    int src = ei[idx];
    int dst = ei[N_EDGES + idx];
    float scale = rk * w[idx];
    int pos = atomicAdd(&cursors[src], 1);
    recs[pos] = make_int2(dst | (set << 17), __float_as_int(scale));
}

extern "C" void kernel_launch(void* const* d_in, const int* in_sizes, int n_in,
                              void* d_out, int out_size, void* d_ws, size_t ws_size,
                              hipStream_t stream) {
    const float* x   = (const float*)d_in[0];
    const int*   ei1 = (const int*)  d_in[1];
    const float* w1  = (const float*)d_in[2];
    const int*   ei2 = (const int*)  d_in[3];
    const float* w2  = (const float*)d_in[4];
    const int*   ei3 = (const int*)  d_in[5];
    const float* w3  = (const float*)d_in[6];
    const float* z0  = (const float*)d_in[7];
    const float* z1  = (const float*)d_in[8];
    const float* z2  = (const float*)d_in[9];
    const float* z3  = (const float*)d_in[10];
    float* out = (float*)d_out;
    char* wsc = (char*)d_ws;

    if (ws_size >= WS_TOTAL_F) {
        int*  ovf_count = (int*) (wsc + WS_OVFCNT);
        int*  bcur      = (int*) (wsc + WS_BCUR);
        int*  bbase     = (int*) (wsc + WS_BBASE);
        int*  bnum      = (int*) (wsc + WS_BNUM);
        int4* ovf       = (int4*)(wsc + WS_OVF);
        int2* tmp       = (int2*)(wsc + WS_TMP);
        int2* frecs     = (int2*)(wsc + WS_FREC);
        int*  offsets   = (int*) (wsc + WS_OFFS);

        hipMemsetAsync(wsc, 0, WS_BBASE, stream);    // ovf_count + bucket cursors
        binA_kernel<<<BINA_BLOCKS, 256, 0, stream>>>(ei1, w1, ei2, w2, ei3, w3,
                                                     z0, z1, z2, z3,
                                                     bcur, ovf_count, ovf, tmp);
        scanB_kernel<<<1, NB, 0, stream>>>(bcur, bbase, bnum, offsets);
        binB_kernel<<<NB, 256, 0, stream>>>(tmp, bbase, bnum, frecs, offsets);
        gatherd_kernel<<<(N_NODES * 64 + 255) / 256, 256, 0, stream>>>(x, offsets, frecs,
                                                                       z0, z1, z2, z3, out);
        ovf_kernel<<<128, 256, 0, stream>>>(x, ovf_count, ovf, out);
    } else {
        int*  counts  = (int*) (wsc + WS_COUNTS);
        int*  offsets = (int*) (wsc + WS_OFFSETS);
        int*  cursors = (int*) (wsc + WS_CURSORS);
        int*  bsum    = (int*) (wsc + WS_BSUM);
        int*  bpre    = (int*) (wsc + WS_BPRE);
        int2* recs    = (int2*)(wsc + WS_RECS);

        hipMemsetAsync(counts, 0, N_NODES * sizeof(int), stream);
        hist_kernel<<<TOT_EDGES / 256, 256, 0, stream>>>(ei1, ei2, ei3, counts);
        scan1_kernel<<<SCAN_BLOCKS, 256, 0, stream>>>(counts, offsets, bsum);
        scan2_kernel<<<1, 512, 0, stream>>>(bsum, bpre);
        scan3_kernel<<<SCAN_BLOCKS, 256, 0, stream>>>(offsets, bpre, cursors);
        fill_kernel<<<TOT_EDGES / 256, 256, 0, stream>>>(ei1, w1, ei2, w2, ei3, w3,
                                                         z0, z1, z2, z3, cursors, recs);
        gatherd_kernel<<<(N_NODES * 64 + 255) / 256, 256, 0, stream>>>(x, offsets, recs,
                                                                       z0, z1, z2, z3, out);
    }
}